// Round 5
// baseline (155.407 us; speedup 1.0000x reference)
//
#include <hip/hip_runtime.h>

// ---------------------------------------------------------------------------
// RCLayer softmax: out = softmax_rows( exp(1/(1+||x_i-c_j||^2)) ) (ALPHA=1)
// M=32768, K=512, N=2048, fp32 out [M][N].
// fp8(e4m3) MFMA GEMM for x.c^T fused with row-softmax; ||x||^2/||c||^2 fp32.
// Round 5: B fragments load DIRECTLY to VGPR banks (no LDS round-trip; the
// round-4 LDS staging had zero cross-wave sharing, so it was pure latency).
// Software pipeline: 4 static register banks, prefetch distance 3 windows,
// compiler-placed counted vmcnts. No manual s_waitcnt anywhere in the loop.
// Regs: 128 AGPR acc + ~32 bank + ~70 working ~= 230 <= 256 (2 waves/SIMD;
// r3 lesson: forcing more via launch_bounds spills acc to scratch).
// ---------------------------------------------------------------------------

typedef __attribute__((ext_vector_type(4)))  float        f32x4;
typedef __attribute__((ext_vector_type(16))) float        f32x16;
typedef __attribute__((ext_vector_type(2)))  unsigned int u32x2;

__device__ __forceinline__ float fastrcp(float x) {
  float r; asm("v_rcp_f32 %0, %1" : "=v"(r) : "v"(x)); return r;
}
__device__ __forceinline__ unsigned int pk4_fp8(f32x4 v) {
  unsigned int u = 0;
  u = __builtin_amdgcn_cvt_pk_fp8_f32(v.x, v.y, u, false);
  u = __builtin_amdgcn_cvt_pk_fp8_f32(v.z, v.w, u, true);
  return u;
}

// ---------------------------------------------------------------------------
// Kernel 1: clusters f32[2048][512] -> fp8 slice image (1MB) + fp32 c2.
// Slice it = kc*8+nc (k-chunk kc 0..7, col-group nc 0..7), 16KB each.
// Within slice: [w 0..7][ko 0..7][l31 0..31] 8B k-octets:
//   off = it*16384 + w*2048 + ko*256 + l31*8
// where col = nc*256 + w*32 + l31, k = kc*64 + ko*8 .. +7.
// ---------------------------------------------------------------------------
__global__ __launch_bounds__(256) void prep_clusters(
    const float* __restrict__ C, unsigned char* __restrict__ Bws,
    float* __restrict__ c2)
{
  const int t   = blockIdx.x * 256 + threadIdx.x;   // 0..131071
  const int n   = t >> 6;                            // cluster (1 wave each)
  const int oct = t & 63;                            // k-octet
  const float* src = C + (size_t)n * 512 + oct * 8;
  f32x4 v0 = *(const f32x4*)src;
  f32x4 v1 = *(const f32x4*)(src + 4);
  float ss = v0.x*v0.x + v0.y*v0.y + v0.z*v0.z + v0.w*v0.w
           + v1.x*v1.x + v1.y*v1.y + v1.z*v1.z + v1.w*v1.w;
  u32x2 h; h.x = pk4_fp8(v0); h.y = pk4_fp8(v1);
  *(u32x2*)(Bws + (size_t)((oct >> 3) * 8 + (n >> 8)) * 16384
                + (size_t)((n >> 5) & 7) * 2048
                + (size_t)(oct & 7) * 256 + (size_t)(n & 31) * 8) = h;
  ss += __shfl_xor(ss, 1);  ss += __shfl_xor(ss, 2);  ss += __shfl_xor(ss, 4);
  ss += __shfl_xor(ss, 8);  ss += __shfl_xor(ss, 16); ss += __shfl_xor(ss, 32);
  if ((threadIdx.x & 63) == 0) c2[n] = ss;
}

// ---------------------------------------------------------------------------
// Kernel 2: fused GEMM + softmax. Block = 32 rows x 2048 cols, 8 waves.
// Wave w consumes per window one 2KB slice-part: 4 x (512B wave-coalesced
// global_load_dwordx2) straight to VGPR banks. 64 windows, distance-3 banks.
// ---------------------------------------------------------------------------
__global__ __launch_bounds__(512, 2) void fused_kernel(
    const float* __restrict__ A, const unsigned char* __restrict__ Bws,
    const float* __restrict__ c2, float* __restrict__ out)
{
  __shared__ __align__(16) unsigned char A_sh[64 * 264];   // 16.5KB fp8 (padded)
  __shared__ float x2_lds[32];
  __shared__ float wsum[8][32];
  __shared__ float inv_lds[32];

  const int tid  = threadIdx.x;
  const int wave = tid >> 6;
  const int lane = tid & 63;
  const int l31  = lane & 31;
  const int hi   = lane >> 5;
  const int brow = blockIdx.x * 32;

  // ---- A staging: fp32 -> fp8 octet layout in LDS (nt loads), exact x2 ----
  {
    const int r   = tid >> 4;        // row 0..31
    const int seg = tid & 15;        // 32-float segment
    const f32x4* ap = (const f32x4*)(A + (size_t)(brow + r) * 512 + seg * 32);
    float ss = 0.f;
#pragma unroll
    for (int i2 = 0; i2 < 4; ++i2) {
      f32x4 va = __builtin_nontemporal_load(ap + 2 * i2);
      f32x4 vb = __builtin_nontemporal_load(ap + 2 * i2 + 1);
      ss += va.x*va.x + va.y*va.y + va.z*va.z + va.w*va.w
          + vb.x*vb.x + vb.y*vb.y + vb.z*vb.z + vb.w*vb.w;
      u32x2 h; h.x = pk4_fp8(va); h.y = pk4_fp8(vb);
      *(u32x2*)(A_sh + (seg * 4 + i2) * 264 + r * 8) = h;
    }
    ss += __shfl_xor(ss, 1); ss += __shfl_xor(ss, 2);
    ss += __shfl_xor(ss, 4); ss += __shfl_xor(ss, 8);
    if (seg == 0) x2_lds[r] = ss;
  }
  __syncthreads();

  // ---- per-lane A-fragment offsets; B per-lane global base ----
  int off_a[4];
#pragma unroll
  for (int ks = 0; ks < 4; ++ks) off_a[ks] = (ks * 2 + hi) * 264 + l31 * 8;

  // lane's byte base within a slice: wave part + ko(hi) part + col part
  const unsigned char* bp = Bws + wave * 2048 + hi * 256 + l31 * 8;

  long b[4][4];   // [bank][ks] — all indices compile-time after unroll

#define PF(GP, BK) {                                                           \
    b[BK][0] = *(const long*)(GP);                                             \
    b[BK][1] = *(const long*)((GP) + 512);                                     \
    b[BK][2] = *(const long*)((GP) + 1024);                                    \
    b[BK][3] = *(const long*)((GP) + 1536); }

  PF(bp, 0); PF(bp + 16384, 1); PF(bp + 32768, 2);
  const unsigned char* gpf = bp + 3 * 16384;   // next window to prefetch

  f32x16 acc[8];
#pragma unroll
  for (int i = 0; i < 8; ++i)
#pragma unroll
    for (int j = 0; j < 16; ++j) acc[i][j] = 0.f;

  // ---- steady state: kc 0..6 (prefetch always valid: w+3 <= 58) ----
  for (int kc = 0; kc < 7; ++kc) {
    long af[4];
#pragma unroll
    for (int ks = 0; ks < 4; ++ks)
      af[ks] = *(const long*)(A_sh + kc * 2112 + off_a[ks]);
#pragma unroll
    for (int nc = 0; nc < 8; ++nc) {
      PF(gpf, (nc + 3) & 3);         // window w+3 into the bank freed at w-1
      gpf += 16384;
#pragma unroll
      for (int ks = 0; ks < 4; ++ks)
        acc[nc] = __builtin_amdgcn_mfma_f32_32x32x16_fp8_fp8(
            af[ks], b[nc & 3][ks], acc[nc], 0, 0, 0);
    }
  }
  // ---- tail kc = 7: prefetch only while windows remain (nc <= 4) ----
  {
    long af[4];
#pragma unroll
    for (int ks = 0; ks < 4; ++ks)
      af[ks] = *(const long*)(A_sh + 7 * 2112 + off_a[ks]);
#pragma unroll
    for (int nc = 0; nc < 8; ++nc) {
      if (nc <= 4) { PF(gpf, (nc + 3) & 3); gpf += 16384; }
#pragma unroll
      for (int ks = 0; ks < 4; ++ks)
        acc[nc] = __builtin_amdgcn_mfma_f32_32x32x16_fp8_fp8(
            af[ks], b[nc & 3][ks], acc[nc], 0, 0, 0);
    }
  }
#undef PF

  // ---- epilogue: d2 -> q -> exp, row-softmax, nt-write ----
  // C/D layout: col = lane&31, row = (r&3) + 8*(r>>2) + 4*hi
  f32x4 x2v[4];
#pragma unroll
  for (int g = 0; g < 4; ++g) x2v[g] = *(const f32x4*)&x2_lds[8 * g + 4 * hi];
  float c2v[8];
#pragma unroll
  for (int nc = 0; nc < 8; ++nc) c2v[nc] = c2[nc * 256 + wave * 32 + l31];

  float p[16];
#pragma unroll
  for (int r = 0; r < 16; ++r) p[r] = 0.f;
#pragma unroll
  for (int nc = 0; nc < 8; ++nc) {
#pragma unroll
    for (int r = 0; r < 16; ++r) {
      float d2 = x2v[r >> 2][r & 3] + c2v[nc] - 2.f * acc[nc][r];
      d2 = fmaxf(d2, 0.f);
      float q = fastrcp(1.f + d2);
      float e = __expf(q);
      acc[nc][r] = e;
      p[r] += e;
    }
  }
#pragma unroll
  for (int r = 0; r < 16; ++r) {
    p[r] += __shfl_xor(p[r], 1);  p[r] += __shfl_xor(p[r], 2);
    p[r] += __shfl_xor(p[r], 4);  p[r] += __shfl_xor(p[r], 8);
    p[r] += __shfl_xor(p[r], 16);
  }
  if (l31 == 0) {
#pragma unroll
    for (int r = 0; r < 16; ++r)
      wsum[wave][(r & 3) + 8 * (r >> 2) + 4 * hi] = p[r];
  }
  __syncthreads();
  if (tid < 32) {
    float t = 0.f;
#pragma unroll
    for (int w = 0; w < 8; ++w) t += wsum[w][tid];
    inv_lds[tid] = fastrcp(t);
  }
  __syncthreads();
  f32x4 invv[4];
#pragma unroll
  for (int g = 0; g < 4; ++g) invv[g] = *(const f32x4*)&inv_lds[8 * g + 4 * hi];

  float* outp = out + (size_t)(brow + 4 * hi) * 2048 + wave * 32 + l31;
#pragma unroll
  for (int nc = 0; nc < 8; ++nc) {
#pragma unroll
    for (int r = 0; r < 16; ++r) {
      const int roff = (r & 3) + 8 * (r >> 2);
      __builtin_nontemporal_store(acc[nc][r] * invv[r >> 2][r & 3],
                                  outp + (size_t)roff * 2048 + nc * 256);
    }
  }
}

// ---------------------------------------------------------------------------
extern "C" void kernel_launch(void* const* d_in, const int* in_sizes, int n_in,
                              void* d_out, int out_size, void* d_ws, size_t ws_size,
                              hipStream_t stream) {
  const float* inputs   = (const float*)d_in[0];   // [32768][512] f32
  const float* clusters = (const float*)d_in[1];   // [2048][512] f32
  float* out = (float*)d_out;                      // [32768][2048] f32
  unsigned char* Bws = (unsigned char*)d_ws;               // 1MB fp8 image
  float* c2 = (float*)((char*)d_ws + (1u << 20));          // 8KB fp32
  prep_clusters<<<512, 256, 0, stream>>>(clusters, Bws, c2);
  fused_kernel<<<1024, 512, 0, stream>>>(inputs, Bws, c2, out);
}

// Round 6
// 135.713 us; speedup vs baseline: 1.1451x; 1.1451x over previous
//
#include <hip/hip_runtime.h>

// ---------------------------------------------------------------------------
// RCLayer softmax: out = softmax_rows( exp(1/(1+||x_i-c_j||^2)) ) (ALPHA=1)
// M=32768, K=512, N=2048, fp32 out [M][N].
// fp8(e4m3) MFMA GEMM for x.c^T fused with row-softmax; ||x||^2/||c||^2 fp32.
// Round 6: OCCUPANCY 2x. r2/r4/r5 all ~150us with every pipe <25% busy ->
// latency-bound at 2 waves/SIMD (acc=128 regs forced that). Fix: 16 waves
// per block (1024 thr), each wave owns 4x32 cols -> acc=64 regs/lane,
// total ~100 < 128 -> 4 waves/SIMD via launch_bounds(1024,4), no spill
// (r3 lesson respected: 64+working fits 128, unlike r3's 128+working).
// B delivery keeps the best-so-far r4 structure: per-wave LDS ring via
// global_load_lds, barrier-free K-loop, counted vmcnt(4), tail 4/2/0.
// ---------------------------------------------------------------------------

typedef __attribute__((ext_vector_type(4)))  float        f32x4;
typedef __attribute__((ext_vector_type(16))) float        f32x16;
typedef __attribute__((ext_vector_type(2)))  unsigned int u32x2;

#define AS1 __attribute__((address_space(1)))
#define AS3 __attribute__((address_space(3)))

__device__ __forceinline__ void gl2lds16(const void* g, void* l) {
  // async global->LDS, 16B/lane; LDS dest = uniform base + lane*16
  __builtin_amdgcn_global_load_lds((const AS1 unsigned int*)g,
                                   (AS3 unsigned int*)l, 16, 0, 0);
}
__device__ __forceinline__ float fastrcp(float x) {
  float r; asm("v_rcp_f32 %0, %1" : "=v"(r) : "v"(x)); return r;
}
__device__ __forceinline__ unsigned int pk4_fp8(f32x4 v) {
  unsigned int u = 0;
  u = __builtin_amdgcn_cvt_pk_fp8_f32(v.x, v.y, u, false);
  u = __builtin_amdgcn_cvt_pk_fp8_f32(v.z, v.w, u, true);
  return u;
}

// ---------------------------------------------------------------------------
// Kernel 1: clusters f32[2048][512] -> fp8 slice image (1MB) + fp32 c2.
// Slice it = kc*8+nc (k-chunk kc 0..7, col-group nc 0..7), 16KB each.
// Within slice: [w8 0..7][ko 0..7][l31 0..31] 8B k-octets:
//   off = it*16384 + w8*2048 + ko*256 + l31*8
// where col = nc*256 + w8*32 + l31, k = kc*64 + ko*8 .. +7.
// ---------------------------------------------------------------------------
__global__ __launch_bounds__(256) void prep_clusters(
    const float* __restrict__ C, unsigned char* __restrict__ Bws,
    float* __restrict__ c2)
{
  const int t   = blockIdx.x * 256 + threadIdx.x;   // 0..131071
  const int n   = t >> 6;                            // cluster (1 wave each)
  const int oct = t & 63;                            // k-octet
  const float* src = C + (size_t)n * 512 + oct * 8;
  f32x4 v0 = *(const f32x4*)src;
  f32x4 v1 = *(const f32x4*)(src + 4);
  float ss = v0.x*v0.x + v0.y*v0.y + v0.z*v0.z + v0.w*v0.w
           + v1.x*v1.x + v1.y*v1.y + v1.z*v1.z + v1.w*v1.w;
  u32x2 h; h.x = pk4_fp8(v0); h.y = pk4_fp8(v1);
  *(u32x2*)(Bws + (size_t)((oct >> 3) * 8 + (n >> 8)) * 16384
                + (size_t)((n >> 5) & 7) * 2048
                + (size_t)(oct & 7) * 256 + (size_t)(n & 31) * 8) = h;
  ss += __shfl_xor(ss, 1);  ss += __shfl_xor(ss, 2);  ss += __shfl_xor(ss, 4);
  ss += __shfl_xor(ss, 8);  ss += __shfl_xor(ss, 16); ss += __shfl_xor(ss, 32);
  if ((threadIdx.x & 63) == 0) c2[n] = ss;
}

// ---------------------------------------------------------------------------
// Kernel 2: fused GEMM + softmax. Block = 32 rows x 2048 cols, 16 waves.
// Wave w (h=w>>3, w8=w&7) owns cols g*512 + w*32 + l31, g=0..3.
// Window (kc,g) <-> image slice it = kc*8 + 2g + h, wave-part w8.
// 32 windows/wave, per-wave 4-slot LDS ring, NO barriers in the K-loop.
// ---------------------------------------------------------------------------
__global__ __launch_bounds__(1024, 4) void fused_kernel(
    const float* __restrict__ A, const unsigned char* __restrict__ Bws,
    const float* __restrict__ c2, float* __restrict__ out)
{
  __shared__ __align__(16) unsigned char A_sh[64 * 264];     // 16.5KB fp8 (padded)
  __shared__ __align__(16) unsigned char B_sh[16 * 4 * 2048]; // 128KB: 16 waves x 4-slot ring
  __shared__ float x2_lds[32];
  __shared__ float wsum[16][32];
  __shared__ float inv_lds[32];

  const int tid  = threadIdx.x;
  const int wave = tid >> 6;
  const int lane = tid & 63;
  const int l31  = lane & 31;
  const int hi   = lane >> 5;
  const int brow = blockIdx.x * 32;

  // ---- A staging: fp32 -> fp8 octet layout in LDS (nt loads), exact x2 ----
  {
    const int r   = tid >> 5;        // row 0..31 (32 threads/row)
    const int seg = tid & 31;        // 16-float segment
    const f32x4* ap = (const f32x4*)(A + (size_t)(brow + r) * 512 + seg * 16);
    float ss = 0.f;
#pragma unroll
    for (int i2 = 0; i2 < 2; ++i2) {
      f32x4 va = __builtin_nontemporal_load(ap + 2 * i2);
      f32x4 vb = __builtin_nontemporal_load(ap + 2 * i2 + 1);
      ss += va.x*va.x + va.y*va.y + va.z*va.z + va.w*va.w
          + vb.x*vb.x + vb.y*vb.y + vb.z*vb.z + vb.w*vb.w;
      u32x2 h; h.x = pk4_fp8(va); h.y = pk4_fp8(vb);
      *(u32x2*)(A_sh + (seg * 2 + i2) * 264 + r * 8) = h;
    }
    ss += __shfl_xor(ss, 1); ss += __shfl_xor(ss, 2);
    ss += __shfl_xor(ss, 4); ss += __shfl_xor(ss, 8); ss += __shfl_xor(ss, 16);
    if (seg == 0) x2_lds[r] = ss;
  }

  // ---- per-wave ring + fragment offsets (all lane-consecutive reads) ----
  unsigned char* ring = B_sh + wave * 8192;
  const int h  = wave >> 3;         // upper/lower 8-wave half
  const int w8 = wave & 7;          // part within a slice
  int off_a[4], off_bs[4];
#pragma unroll
  for (int ks = 0; ks < 4; ++ks) {
    off_a[ks]  = (ks * 2 + hi) * 264 + l31 * 8;
    off_bs[ks] = (ks * 2 + hi) * 256 + l31 * 8;
  }

  // window win = kc*4 + g  ->  slice it = kc*8 + 2g + h
#define STAGE_W(WIN) {                                                         \
    const int it_ = (((WIN) >> 2) << 3) + (((WIN) & 3) << 1) + h;              \
    const unsigned char* g_ = Bws + (size_t)it_ * 16384                        \
                            + w8 * 2048 + lane * 16;                           \
    unsigned char* l_ = ring + ((WIN) & 3) * 2048;                             \
    gl2lds16(g_, l_);  gl2lds16(g_ + 1024, l_ + 1024); }

  STAGE_W(0); STAGE_W(1); STAGE_W(2);

  __syncthreads();   // A_sh / x2_lds ready (B ring is per-wave, no barrier)

  f32x16 acc[4];
#pragma unroll
  for (int i = 0; i < 4; ++i)
#pragma unroll
    for (int j = 0; j < 16; ++j) acc[i][j] = 0.f;

  // ---- steady state: kc 0..6 (stage win+3 always valid: <= 30) ----
  for (int kc = 0; kc < 7; ++kc) {
    long af[4];
#pragma unroll
    for (int ks = 0; ks < 4; ++ks)
      af[ks] = *(const long*)(A_sh + kc * 2112 + off_a[ks]);
#pragma unroll
    for (int g = 0; g < 4; ++g) {
      asm volatile("s_waitcnt vmcnt(4)" ::: "memory");   // window `win` landed
      __builtin_amdgcn_sched_barrier(0);
      STAGE_W(kc * 4 + g + 3);                           // refill ring
      const unsigned char* bp = ring + (g & 3) * 2048;
#pragma unroll
      for (int ks = 0; ks < 4; ++ks) {
        long b = *(const long*)(bp + off_bs[ks]);
        acc[g] = __builtin_amdgcn_mfma_f32_32x32x16_fp8_fp8(af[ks], b, acc[g], 0, 0, 0);
      }
    }
  }
  // ---- tail kc = 7: windows 28..31, drain 4/4/2/0 ----
  {
    long af[4];
#pragma unroll
    for (int ks = 0; ks < 4; ++ks)
      af[ks] = *(const long*)(A_sh + 7 * 2112 + off_a[ks]);
#pragma unroll
    for (int g = 0; g < 4; ++g) {
      if (g <= 1)      { asm volatile("s_waitcnt vmcnt(4)" ::: "memory"); }
      else if (g == 2) { asm volatile("s_waitcnt vmcnt(2)" ::: "memory"); }
      else             { asm volatile("s_waitcnt vmcnt(0)" ::: "memory"); }
      __builtin_amdgcn_sched_barrier(0);
      if (g == 0) STAGE_W(31);
      const unsigned char* bp = ring + (g & 3) * 2048;
#pragma unroll
      for (int ks = 0; ks < 4; ++ks) {
        long b = *(const long*)(bp + off_bs[ks]);
        acc[g] = __builtin_amdgcn_mfma_f32_32x32x16_fp8_fp8(af[ks], b, acc[g], 0, 0, 0);
      }
    }
  }
#undef STAGE_W

  // ---- epilogue: d2 -> q -> exp, row-softmax, nt-write ----
  // C/D layout: col = lane&31, row = (r&3) + 8*(r>>2) + 4*hi
  f32x4 x2v[4];
#pragma unroll
  for (int gg = 0; gg < 4; ++gg) x2v[gg] = *(const f32x4*)&x2_lds[8 * gg + 4 * hi];
  float c2v[4];
#pragma unroll
  for (int g = 0; g < 4; ++g) c2v[g] = c2[g * 512 + wave * 32 + l31];

  float p[16];
#pragma unroll
  for (int r = 0; r < 16; ++r) p[r] = 0.f;
#pragma unroll
  for (int g = 0; g < 4; ++g) {
#pragma unroll
    for (int r = 0; r < 16; ++r) {
      float d2 = x2v[r >> 2][r & 3] + c2v[g] - 2.f * acc[g][r];
      d2 = fmaxf(d2, 0.f);
      float q = fastrcp(1.f + d2);
      float e = __expf(q);
      acc[g][r] = e;
      p[r] += e;
    }
  }
#pragma unroll
  for (int r = 0; r < 16; ++r) {
    p[r] += __shfl_xor(p[r], 1);  p[r] += __shfl_xor(p[r], 2);
    p[r] += __shfl_xor(p[r], 4);  p[r] += __shfl_xor(p[r], 8);
    p[r] += __shfl_xor(p[r], 16);
  }
  if (l31 == 0) {
#pragma unroll
    for (int r = 0; r < 16; ++r)
      wsum[wave][(r & 3) + 8 * (r >> 2) + 4 * hi] = p[r];
  }
  __syncthreads();
  if (tid < 32) {
    float t = 0.f;
#pragma unroll
    for (int w = 0; w < 16; ++w) t += wsum[w][tid];
    inv_lds[tid] = fastrcp(t);
  }
  __syncthreads();
  f32x4 invv[4];
#pragma unroll
  for (int gg = 0; gg < 4; ++gg) invv[gg] = *(const f32x4*)&inv_lds[8 * gg + 4 * hi];

  float* outp = out + (size_t)(brow + 4 * hi) * 2048 + wave * 32 + l31;
#pragma unroll
  for (int g = 0; g < 4; ++g) {
#pragma unroll
    for (int r = 0; r < 16; ++r) {
      const int roff = (r & 3) + 8 * (r >> 2);
      __builtin_nontemporal_store(acc[g][r] * invv[r >> 2][r & 3],
                                  outp + (size_t)roff * 2048 + g * 512);
    }
  }
}

// ---------------------------------------------------------------------------
extern "C" void kernel_launch(void* const* d_in, const int* in_sizes, int n_in,
                              void* d_out, int out_size, void* d_ws, size_t ws_size,
                              hipStream_t stream) {
  const float* inputs   = (const float*)d_in[0];   // [32768][512] f32
  const float* clusters = (const float*)d_in[1];   // [2048][512] f32
  float* out = (float*)d_out;                      // [32768][2048] f32
  unsigned char* Bws = (unsigned char*)d_ws;               // 1MB fp8 image
  float* c2 = (float*)((char*)d_ws + (1u << 20));          // 8KB fp32
  prep_clusters<<<512, 256, 0, stream>>>(clusters, Bws, c2);
  fused_kernel<<<1024, 1024, 0, stream>>>(inputs, Bws, c2, out);
}

// Round 7
// 128.456 us; speedup vs baseline: 1.2098x; 1.0565x over previous
//
#include <hip/hip_runtime.h>

// ---------------------------------------------------------------------------
// RCLayer softmax: out = softmax_rows( exp(1/(1+||x_i-c_j||^2)) ) (ALPHA=1)
// M=32768, K=512, N=2048, fp32 out [M][N].
// Round 7: MX-scaled fp8 MFMA (32x32x64, unity scale) — halves mandatory
// MFMA time (27.6us -> 14.7us; m119-corrected per-CU cycle model) and
// replaces the 4-deep dependent 32x32x16 chain per window with ONE MFMA.
// A/B fragments use the IDENTICAL (half,byte)->k mapping (octets 4*hi+j),
// so contraction is correct for any internal HW k-permutation.
// Everything else identical to r6: 16 waves/block (4/SIMD), per-wave 4-slot
// LDS ring via global_load_lds, barrier-free K-loop, vmcnt(4), tail 4/2/0.
// ---------------------------------------------------------------------------

typedef __attribute__((ext_vector_type(4)))  float        f32x4;
typedef __attribute__((ext_vector_type(16))) float        f32x16;
typedef __attribute__((ext_vector_type(8)))  int          i32x8;
typedef __attribute__((ext_vector_type(2)))  unsigned int u32x2;

#define AS1 __attribute__((address_space(1)))
#define AS3 __attribute__((address_space(3)))

__device__ __forceinline__ void gl2lds16(const void* g, void* l) {
  // async global->LDS, 16B/lane; LDS dest = uniform base + lane*16
  __builtin_amdgcn_global_load_lds((const AS1 unsigned int*)g,
                                   (AS3 unsigned int*)l, 16, 0, 0);
}
__device__ __forceinline__ float fastrcp(float x) {
  float r; asm("v_rcp_f32 %0, %1" : "=v"(r) : "v"(x)); return r;
}
__device__ __forceinline__ unsigned int pk4_fp8(f32x4 v) {
  unsigned int u = 0;
  u = __builtin_amdgcn_cvt_pk_fp8_f32(v.x, v.y, u, false);
  u = __builtin_amdgcn_cvt_pk_fp8_f32(v.z, v.w, u, true);
  return u;
}

union frag8 { long l[4]; i32x8 v; };

// ---------------------------------------------------------------------------
// Kernel 1: clusters f32[2048][512] -> fp8 slice image (1MB) + fp32 c2.
// Slice it = kc*8+nc (k-chunk kc 0..7, col-group nc 0..7), 16KB each.
// Within slice: [w8 0..7][ko 0..7][l31 0..31] 8B k-octets:
//   off = it*16384 + w8*2048 + ko*256 + l31*8
// where col = nc*256 + w8*32 + l31, k = kc*64 + ko*8 .. +7.
// ---------------------------------------------------------------------------
__global__ __launch_bounds__(256) void prep_clusters(
    const float* __restrict__ C, unsigned char* __restrict__ Bws,
    float* __restrict__ c2)
{
  const int t   = blockIdx.x * 256 + threadIdx.x;   // 0..131071
  const int n   = t >> 6;                            // cluster (1 wave each)
  const int oct = t & 63;                            // k-octet
  const float* src = C + (size_t)n * 512 + oct * 8;
  f32x4 v0 = *(const f32x4*)src;
  f32x4 v1 = *(const f32x4*)(src + 4);
  float ss = v0.x*v0.x + v0.y*v0.y + v0.z*v0.z + v0.w*v0.w
           + v1.x*v1.x + v1.y*v1.y + v1.z*v1.z + v1.w*v1.w;
  u32x2 h; h.x = pk4_fp8(v0); h.y = pk4_fp8(v1);
  *(u32x2*)(Bws + (size_t)((oct >> 3) * 8 + (n >> 8)) * 16384
                + (size_t)((n >> 5) & 7) * 2048
                + (size_t)(oct & 7) * 256 + (size_t)(n & 31) * 8) = h;
  ss += __shfl_xor(ss, 1);  ss += __shfl_xor(ss, 2);  ss += __shfl_xor(ss, 4);
  ss += __shfl_xor(ss, 8);  ss += __shfl_xor(ss, 16); ss += __shfl_xor(ss, 32);
  if ((threadIdx.x & 63) == 0) c2[n] = ss;
}

// ---------------------------------------------------------------------------
// Kernel 2: fused GEMM + softmax. Block = 32 rows x 2048 cols, 16 waves.
// Wave w (h=w>>3, w8=w&7) owns cols g*512 + w*32 + l31, g=0..3.
// Window (kc,g) <-> image slice it = kc*8 + 2g + h, wave-part w8.
// 32 windows/wave, ONE 32x32x64 MX-MFMA each. Per-wave 4-slot LDS ring,
// NO barriers in the K-loop.
// ---------------------------------------------------------------------------
__global__ __launch_bounds__(1024, 4) void fused_kernel(
    const float* __restrict__ A, const unsigned char* __restrict__ Bws,
    const float* __restrict__ c2, float* __restrict__ out)
{
  __shared__ __align__(16) unsigned char A_sh[64 * 264];     // 16.5KB fp8 (padded)
  __shared__ __align__(16) unsigned char B_sh[16 * 4 * 2048]; // 128KB ring
  __shared__ float x2_lds[32];
  __shared__ float wsum[16][32];
  __shared__ float inv_lds[32];

  const int tid  = threadIdx.x;
  const int wave = tid >> 6;
  const int lane = tid & 63;
  const int l31  = lane & 31;
  const int hi   = lane >> 5;
  const int brow = blockIdx.x * 32;

  // ---- A staging: fp32 -> fp8 octet layout in LDS (nt loads), exact x2 ----
  {
    const int r   = tid >> 5;        // row 0..31 (32 threads/row)
    const int seg = tid & 31;        // 16-float segment
    const f32x4* ap = (const f32x4*)(A + (size_t)(brow + r) * 512 + seg * 16);
    float ss = 0.f;
#pragma unroll
    for (int i2 = 0; i2 < 2; ++i2) {
      f32x4 va = __builtin_nontemporal_load(ap + 2 * i2);
      f32x4 vb = __builtin_nontemporal_load(ap + 2 * i2 + 1);
      ss += va.x*va.x + va.y*va.y + va.z*va.z + va.w*va.w
          + vb.x*vb.x + vb.y*vb.y + vb.z*vb.z + vb.w*vb.w;
      u32x2 h; h.x = pk4_fp8(va); h.y = pk4_fp8(vb);
      *(u32x2*)(A_sh + (seg * 2 + i2) * 264 + r * 8) = h;
    }
    ss += __shfl_xor(ss, 1); ss += __shfl_xor(ss, 2);
    ss += __shfl_xor(ss, 4); ss += __shfl_xor(ss, 8); ss += __shfl_xor(ss, 16);
    if (seg == 0) x2_lds[r] = ss;
  }

  // ---- per-wave ring + fragment offsets ----
  // Fragment k-mapping (A and B IDENTICAL): byte (j*8+m) of the v8i32 frag
  // = k-octet (4*hi + j), element m  ->  correct for any HW k-permutation.
  unsigned char* ring = B_sh + wave * 8192;
  const int h  = wave >> 3;         // upper/lower 8-wave half
  const int w8 = wave & 7;          // part within a slice
  int off_a[4], off_bs[4];
#pragma unroll
  for (int j = 0; j < 4; ++j) {
    off_a[j]  = (4 * hi + j) * 264 + l31 * 8;
    off_bs[j] = (4 * hi + j) * 256 + l31 * 8;
  }

  // window win = kc*4 + g  ->  slice it = kc*8 + 2g + h
#define STAGE_W(WIN) {                                                         \
    const int it_ = (((WIN) >> 2) << 3) + (((WIN) & 3) << 1) + h;              \
    const unsigned char* g_ = Bws + (size_t)it_ * 16384                        \
                            + w8 * 2048 + lane * 16;                           \
    unsigned char* l_ = ring + ((WIN) & 3) * 2048;                             \
    gl2lds16(g_, l_);  gl2lds16(g_ + 1024, l_ + 1024); }

  STAGE_W(0); STAGE_W(1); STAGE_W(2);

  __syncthreads();   // A_sh / x2_lds ready (B ring is per-wave, no barrier)

  f32x16 acc[4];
#pragma unroll
  for (int i = 0; i < 4; ++i)
#pragma unroll
    for (int j = 0; j < 16; ++j) acc[i][j] = 0.f;

  // ---- steady state: kc 0..6 (stage win+3 always valid: <= 30) ----
  for (int kc = 0; kc < 7; ++kc) {
    frag8 a8;
#pragma unroll
    for (int j = 0; j < 4; ++j)
      a8.l[j] = *(const long*)(A_sh + kc * 2112 + off_a[j]);
#pragma unroll
    for (int g = 0; g < 4; ++g) {
      asm volatile("s_waitcnt vmcnt(4)" ::: "memory");   // window `win` landed
      __builtin_amdgcn_sched_barrier(0);
      STAGE_W(kc * 4 + g + 3);                           // refill ring
      const unsigned char* bp = ring + (g & 3) * 2048;
      frag8 b8;
#pragma unroll
      for (int j = 0; j < 4; ++j)
        b8.l[j] = *(const long*)(bp + off_bs[j]);
      acc[g] = __builtin_amdgcn_mfma_scale_f32_32x32x64_f8f6f4(
          a8.v, b8.v, acc[g], 0, 0, 0, 127, 0, 127);
    }
  }
  // ---- tail kc = 7: windows 28..31, drain 4/4/2/0 ----
  {
    frag8 a8;
#pragma unroll
    for (int j = 0; j < 4; ++j)
      a8.l[j] = *(const long*)(A_sh + 7 * 2112 + off_a[j]);
#pragma unroll
    for (int g = 0; g < 4; ++g) {
      if (g <= 1)      { asm volatile("s_waitcnt vmcnt(4)" ::: "memory"); }
      else if (g == 2) { asm volatile("s_waitcnt vmcnt(2)" ::: "memory"); }
      else             { asm volatile("s_waitcnt vmcnt(0)" ::: "memory"); }
      __builtin_amdgcn_sched_barrier(0);
      if (g == 0) STAGE_W(31);
      const unsigned char* bp = ring + (g & 3) * 2048;
      frag8 b8;
#pragma unroll
      for (int j = 0; j < 4; ++j)
        b8.l[j] = *(const long*)(bp + off_bs[j]);
      acc[g] = __builtin_amdgcn_mfma_scale_f32_32x32x64_f8f6f4(
          a8.v, b8.v, acc[g], 0, 0, 0, 127, 0, 127);
    }
  }
#undef STAGE_W

  // ---- epilogue: d2 -> q -> exp, row-softmax, nt-write ----
  // C/D layout (shape-determined): col = lane&31, row = (r&3)+8*(r>>2)+4*hi
  f32x4 x2v[4];
#pragma unroll
  for (int gg = 0; gg < 4; ++gg) x2v[gg] = *(const f32x4*)&x2_lds[8 * gg + 4 * hi];
  float c2v[4];
#pragma unroll
  for (int g = 0; g < 4; ++g) c2v[g] = c2[g * 512 + wave * 32 + l31];

  float p[16];
#pragma unroll
  for (int r = 0; r < 16; ++r) p[r] = 0.f;
#pragma unroll
  for (int g = 0; g < 4; ++g) {
#pragma unroll
    for (int r = 0; r < 16; ++r) {
      float d2 = x2v[r >> 2][r & 3] + c2v[g] - 2.f * acc[g][r];
      d2 = fmaxf(d2, 0.f);
      float q = fastrcp(1.f + d2);
      float e = __expf(q);
      acc[g][r] = e;
      p[r] += e;
    }
  }
#pragma unroll
  for (int r = 0; r < 16; ++r) {
    p[r] += __shfl_xor(p[r], 1);  p[r] += __shfl_xor(p[r], 2);
    p[r] += __shfl_xor(p[r], 4);  p[r] += __shfl_xor(p[r], 8);
    p[r] += __shfl_xor(p[r], 16);
  }
  if (l31 == 0) {
#pragma unroll
    for (int r = 0; r < 16; ++r)
      wsum[wave][(r & 3) + 8 * (r >> 2) + 4 * hi] = p[r];
  }
  __syncthreads();
  if (tid < 32) {
    float t = 0.f;
#pragma unroll
    for (int w = 0; w < 16; ++w) t += wsum[w][tid];
    inv_lds[tid] = fastrcp(t);
  }
  __syncthreads();
  f32x4 invv[4];
#pragma unroll
  for (int gg = 0; gg < 4; ++gg) invv[gg] = *(const f32x4*)&inv_lds[8 * gg + 4 * hi];

  float* outp = out + (size_t)(brow + 4 * hi) * 2048 + wave * 32 + l31;
#pragma unroll
  for (int g = 0; g < 4; ++g) {
#pragma unroll
    for (int r = 0; r < 16; ++r) {
      const int roff = (r & 3) + 8 * (r >> 2);
      __builtin_nontemporal_store(acc[g][r] * invv[r >> 2][r & 3],
                                  outp + (size_t)roff * 2048 + g * 512);
    }
  }
}

// ---------------------------------------------------------------------------
extern "C" void kernel_launch(void* const* d_in, const int* in_sizes, int n_in,
                              void* d_out, int out_size, void* d_ws, size_t ws_size,
                              hipStream_t stream) {
  const float* inputs   = (const float*)d_in[0];   // [32768][512] f32
  const float* clusters = (const float*)d_in[1];   // [2048][512] f32
  float* out = (float*)d_out;                      // [32768][2048] f32
  unsigned char* Bws = (unsigned char*)d_ws;               // 1MB fp8 image
  float* c2 = (float*)((char*)d_ws + (1u << 20));          // 8KB fp32
  prep_clusters<<<512, 256, 0, stream>>>(clusters, Bws, c2);
  fused_kernel<<<1024, 1024, 0, stream>>>(inputs, Bws, c2, out);
}

// Round 8
// 110.847 us; speedup vs baseline: 1.4020x; 1.1589x over previous
//
#include <hip/hip_runtime.h>

// ---------------------------------------------------------------------------
// RCLayer softmax: out = softmax_rows( exp(1/(1+||x_i-c_j||^2)) ) (ALPHA=1)
// M=32768, K=512, N=2048, fp32 out [M][N].
// Round 8: FP4 (e2m1, unity scale) operands for the x.c^T GEMM. B cache-read
// volume (nblocks x image = 1 GB at fp8) is the identified wall; fp4 halves
// it to 512 MB and doubles MFMA rate. ||x||^2/||c||^2 remain exact fp32;
// error analysis: dout ~ 4.9e-10 * dd2, fp4 gives dd2 ~ 13 -> ~6e-9 << 9.8e-6.
// A/B fragments use IDENTICAL linear (lane,nibble)->k maps, so the MFMA
// contraction is correct under any internal HW k-permutation.
// Structure from r6/r7: 16 waves/block (4/SIMD), per-wave LDS ring (now
// 8 slots x 1KB), barrier-free K-loop, ONE global_load_lds + ONE 32x32x64
// MX-MFMA (cbsz=blgp=4 -> fp4) per window, vmcnt(6) steady, exact tail ladder.
// ---------------------------------------------------------------------------

typedef __attribute__((ext_vector_type(4)))  float        f32x4;
typedef __attribute__((ext_vector_type(16))) float        f32x16;
typedef __attribute__((ext_vector_type(8)))  int          i32x8;
typedef __attribute__((ext_vector_type(2)))  unsigned int u32x2;
typedef __attribute__((ext_vector_type(2)))  long         i64x2;

#define AS1 __attribute__((address_space(1)))
#define AS3 __attribute__((address_space(3)))

__device__ __forceinline__ void gl2lds16(const void* g, void* l) {
  // async global->LDS, 16B/lane; LDS dest = uniform base + lane*16
  __builtin_amdgcn_global_load_lds((const AS1 unsigned int*)g,
                                   (AS3 unsigned int*)l, 16, 0, 0);
}
__device__ __forceinline__ float fastrcp(float x) {
  float r; asm("v_rcp_f32 %0, %1" : "=v"(r) : "v"(x)); return r;
}

// f32 -> fp4 e2m1 nibble (sign<<3 | code). Magnitudes {0,.5,1,1.5,2,3,4,6};
// code order == encoding order (E=0:{0,.5} E=1:{1,1.5} E=2:{2,3} E=3:{4,6}).
__device__ __forceinline__ unsigned int nib_fp4(float v) {
  float a = fabsf(v);
  unsigned int code = (unsigned)(a > 0.25f) + (unsigned)(a > 0.75f)
                    + (unsigned)(a > 1.25f) + (unsigned)(a > 1.75f)
                    + (unsigned)(a > 2.5f)  + (unsigned)(a > 3.5f)
                    + (unsigned)(a > 5.0f);
  return code | ((__float_as_uint(v) >> 28) & 8u);
}
__device__ __forceinline__ unsigned int pk8_fp4(f32x4 a, f32x4 b) {
  return  nib_fp4(a.x)        | (nib_fp4(a.y) << 4)
       | (nib_fp4(a.z) << 8)  | (nib_fp4(a.w) << 12)
       | (nib_fp4(b.x) << 16) | (nib_fp4(b.y) << 20)
       | (nib_fp4(b.z) << 24) | (nib_fp4(b.w) << 28);
}

union frag8 { long l[4]; i32x8 v; };

// ---------------------------------------------------------------------------
// Kernel 1: clusters f32[2048][512] -> fp4 slice image (512KB) + fp32 c2.
// Slice it = kc*8+nc (kc 0..7, nc 0..7), 8KB each. Within slice:
// [w8 0..7][hi 0..1][l31 0..31] 16B blocks; nibble i of block = k-offset
// kc*64 + hi*32 + i for col nc*256 + w8*32 + l31.
// ---------------------------------------------------------------------------
__global__ __launch_bounds__(256) void prep_clusters(
    const float* __restrict__ C, unsigned char* __restrict__ Bws,
    float* __restrict__ c2)
{
  const int t   = blockIdx.x * 256 + threadIdx.x;   // 0..131071
  const int n   = t >> 6;                            // cluster (1 wave each)
  const int oct = t & 63;                            // 8-k octet
  const float* src = C + (size_t)n * 512 + oct * 8;
  f32x4 v0 = *(const f32x4*)src;
  f32x4 v1 = *(const f32x4*)(src + 4);
  float ss = v0.x*v0.x + v0.y*v0.y + v0.z*v0.z + v0.w*v0.w
           + v1.x*v1.x + v1.y*v1.y + v1.z*v1.z + v1.w*v1.w;
  const int kc  = oct >> 3;
  const int hi  = (oct & 7) >> 2;
  const int sub = oct & 3;
  const int nc  = n >> 8, w8 = (n >> 5) & 7, l31 = n & 31;
  *(unsigned int*)(Bws + (size_t)(kc * 8 + nc) * 8192
                 + w8 * 1024 + hi * 512 + l31 * 16 + sub * 4) = pk8_fp4(v0, v1);
  ss += __shfl_xor(ss, 1);  ss += __shfl_xor(ss, 2);  ss += __shfl_xor(ss, 4);
  ss += __shfl_xor(ss, 8);  ss += __shfl_xor(ss, 16); ss += __shfl_xor(ss, 32);
  if ((threadIdx.x & 63) == 0) c2[n] = ss;
}

// ---------------------------------------------------------------------------
// Kernel 2: fused GEMM + softmax. Block = 32 rows x 2048 cols, 16 waves.
// Wave w (h=w>>3, w8=w&7) owns cols g*512 + w*32 + l31, g=0..3.
// Window win = kc*4+g  <->  slice it = kc*8 + 2g + h, wave-part w8 (1KB).
// 32 windows/wave, ONE fp4 32x32x64 MX-MFMA each. 8-slot per-wave LDS ring,
// NO barriers in the K-loop, vmcnt(6) steady / 6,6,5,4,3,2,1,0 tail.
// ---------------------------------------------------------------------------
__global__ __launch_bounds__(1024, 4) void fused_kernel(
    const float* __restrict__ A, const unsigned char* __restrict__ Bws,
    const float* __restrict__ c2, float* __restrict__ out)
{
  __shared__ __align__(16) unsigned char A_sh[8 * 1024];      // 8KB fp4 A tile
  __shared__ __align__(16) unsigned char B_sh[16 * 8 * 1024]; // 128KB ring
  __shared__ float x2_lds[32];
  __shared__ float wsum[16][32];
  __shared__ float inv_lds[32];

  const int tid  = threadIdx.x;
  const int wave = tid >> 6;
  const int lane = tid & 63;
  const int l31  = lane & 31;
  const int hi   = lane >> 5;
  const int brow = blockIdx.x * 32;

  // ---- A staging: fp32 -> fp4 in LDS (nt loads), exact fp32 x2 ----
  // A_sh layout: [kc][khalf][row] 16B blocks, nibble i = k kc*64+khalf*32+i.
  {
    const int r   = tid >> 5;        // row 0..31
    const int seg = tid & 31;        // 16-float segment (k = seg*16..+15)
    const f32x4* ap = (const f32x4*)(A + (size_t)(brow + r) * 512 + seg * 16);
    f32x4 v0 = __builtin_nontemporal_load(ap);
    f32x4 v1 = __builtin_nontemporal_load(ap + 1);
    f32x4 v2 = __builtin_nontemporal_load(ap + 2);
    f32x4 v3 = __builtin_nontemporal_load(ap + 3);
    float ss = v0.x*v0.x + v0.y*v0.y + v0.z*v0.z + v0.w*v0.w
             + v1.x*v1.x + v1.y*v1.y + v1.z*v1.z + v1.w*v1.w
             + v2.x*v2.x + v2.y*v2.y + v2.z*v2.z + v2.w*v2.w
             + v3.x*v3.x + v3.y*v3.y + v3.z*v3.z + v3.w*v3.w;
    u32x2 pk; pk.x = pk8_fp4(v0, v1); pk.y = pk8_fp4(v2, v3);
    const int kc = seg >> 2, kh = (seg & 3) >> 1, half = seg & 1;
    *(u32x2*)(A_sh + kc * 1024 + kh * 512 + r * 16 + half * 8) = pk;
    ss += __shfl_xor(ss, 1); ss += __shfl_xor(ss, 2);
    ss += __shfl_xor(ss, 4); ss += __shfl_xor(ss, 8); ss += __shfl_xor(ss, 16);
    if (seg == 0) x2_lds[r] = ss;
  }

  // ---- per-wave ring; per-lane offsets (16B contiguous frags) ----
  unsigned char* ring = B_sh + wave * 8192;
  const int h  = wave >> 3;
  const int w8 = wave & 7;
  const int off_frag = hi * 512 + l31 * 16;   // within A_sh[kc] / ring slot

  // window win = kc*4 + g  ->  slice it = kc*8 + 2g + h
#define STAGE_W(WIN) {                                                         \
    const int it_ = (((WIN) >> 2) << 3) + (((WIN) & 3) << 1) + h;              \
    gl2lds16(Bws + (size_t)it_ * 8192 + w8 * 1024 + lane * 16,                 \
             ring + ((WIN) & 7) * 1024); }
#define WAITV(N) asm volatile("s_waitcnt vmcnt(" #N ")" ::: "memory")

  STAGE_W(0); STAGE_W(1); STAGE_W(2); STAGE_W(3);
  STAGE_W(4); STAGE_W(5); STAGE_W(6);             // 7 in flight

  __syncthreads();   // A_sh / x2_lds ready (B ring is per-wave, no barrier)

  f32x16 acc[4];
#pragma unroll
  for (int i = 0; i < 4; ++i)
#pragma unroll
    for (int j = 0; j < 16; ++j) acc[i][j] = 0.f;

#define DO_MFMA(WIN, G) {                                                      \
    const unsigned char* bp = ring + ((WIN) & 7) * 1024;                       \
    i64x2 bt = *(const i64x2*)(bp + off_frag);                                 \
    frag8 b8; b8.l[0] = bt.x; b8.l[1] = bt.y; b8.l[2] = 0; b8.l[3] = 0;        \
    acc[G] = __builtin_amdgcn_mfma_scale_f32_32x32x64_f8f6f4(                  \
        a8.v, b8.v, acc[G], 4, 4, 0, 127, 0, 127); }

  // ---- steady state: kc 0..5 (stage win+7 <= 31 always valid) ----
  for (int kc = 0; kc < 6; ++kc) {
    frag8 a8;
    { i64x2 at = *(const i64x2*)(A_sh + kc * 1024 + off_frag);
      a8.l[0] = at.x; a8.l[1] = at.y; a8.l[2] = 0; a8.l[3] = 0; }
#pragma unroll
    for (int g = 0; g < 4; ++g) {
      WAITV(6);
      __builtin_amdgcn_sched_barrier(0);
      STAGE_W(kc * 4 + g + 7);
      DO_MFMA(kc * 4 + g, g);
    }
  }
  // ---- kc = 6: windows 24..27 (last stage at win 24 -> slice 31) ----
  {
    frag8 a8;
    { i64x2 at = *(const i64x2*)(A_sh + 6 * 1024 + off_frag);
      a8.l[0] = at.x; a8.l[1] = at.y; a8.l[2] = 0; a8.l[3] = 0; }
    WAITV(6); __builtin_amdgcn_sched_barrier(0); STAGE_W(31); DO_MFMA(24, 0);
    WAITV(6); __builtin_amdgcn_sched_barrier(0);             DO_MFMA(25, 1);
    WAITV(5); __builtin_amdgcn_sched_barrier(0);             DO_MFMA(26, 2);
    WAITV(4); __builtin_amdgcn_sched_barrier(0);             DO_MFMA(27, 3);
  }
  // ---- kc = 7: windows 28..31, drain 3/2/1/0 ----
  {
    frag8 a8;
    { i64x2 at = *(const i64x2*)(A_sh + 7 * 1024 + off_frag);
      a8.l[0] = at.x; a8.l[1] = at.y; a8.l[2] = 0; a8.l[3] = 0; }
    WAITV(3); __builtin_amdgcn_sched_barrier(0); DO_MFMA(28, 0);
    WAITV(2); __builtin_amdgcn_sched_barrier(0); DO_MFMA(29, 1);
    WAITV(1); __builtin_amdgcn_sched_barrier(0); DO_MFMA(30, 2);
    WAITV(0); __builtin_amdgcn_sched_barrier(0); DO_MFMA(31, 3);
  }
#undef DO_MFMA
#undef STAGE_W
#undef WAITV

  // ---- epilogue: d2 -> q -> exp, row-softmax, nt-write ----
  // C/D layout (shape-determined): col = lane&31, row = (r&3)+8*(r>>2)+4*hi
  f32x4 x2v[4];
#pragma unroll
  for (int gg = 0; gg < 4; ++gg) x2v[gg] = *(const f32x4*)&x2_lds[8 * gg + 4 * hi];
  float c2v[4];
#pragma unroll
  for (int g = 0; g < 4; ++g) c2v[g] = c2[g * 512 + wave * 32 + l31];

  float p[16];
#pragma unroll
  for (int r = 0; r < 16; ++r) p[r] = 0.f;
#pragma unroll
  for (int g = 0; g < 4; ++g) {
#pragma unroll
    for (int r = 0; r < 16; ++r) {
      float d2 = x2v[r >> 2][r & 3] + c2v[g] - 2.f * acc[g][r];
      d2 = fmaxf(d2, 0.f);
      float q = fastrcp(1.f + d2);
      float e = __expf(q);
      acc[g][r] = e;
      p[r] += e;
    }
  }
#pragma unroll
  for (int r = 0; r < 16; ++r) {
    p[r] += __shfl_xor(p[r], 1);  p[r] += __shfl_xor(p[r], 2);
    p[r] += __shfl_xor(p[r], 4);  p[r] += __shfl_xor(p[r], 8);
    p[r] += __shfl_xor(p[r], 16);
  }
  if (l31 == 0) {
#pragma unroll
    for (int r = 0; r < 16; ++r)
      wsum[wave][(r & 3) + 8 * (r >> 2) + 4 * hi] = p[r];
  }
  __syncthreads();
  if (tid < 32) {
    float t = 0.f;
#pragma unroll
    for (int w = 0; w < 16; ++w) t += wsum[w][tid];
    inv_lds[tid] = fastrcp(t);
  }
  __syncthreads();
  f32x4 invv[4];
#pragma unroll
  for (int gg = 0; gg < 4; ++gg) invv[gg] = *(const f32x4*)&inv_lds[8 * gg + 4 * hi];

  float* outp = out + (size_t)(brow + 4 * hi) * 2048 + wave * 32 + l31;
#pragma unroll
  for (int g = 0; g < 4; ++g) {
#pragma unroll
    for (int r = 0; r < 16; ++r) {
      const int roff = (r & 3) + 8 * (r >> 2);
      __builtin_nontemporal_store(acc[g][r] * invv[r >> 2][r & 3],
                                  outp + (size_t)roff * 2048 + g * 512);
    }
  }
}

// ---------------------------------------------------------------------------
extern "C" void kernel_launch(void* const* d_in, const int* in_sizes, int n_in,
                              void* d_out, int out_size, void* d_ws, size_t ws_size,
                              hipStream_t stream) {
  const float* inputs   = (const float*)d_in[0];   // [32768][512] f32
  const float* clusters = (const float*)d_in[1];   // [2048][512] f32
  float* out = (float*)d_out;                      // [32768][2048] f32
  unsigned char* Bws = (unsigned char*)d_ws;               // 512KB fp4 image
  float* c2 = (float*)((char*)d_ws + (1u << 20));          // 8KB fp32
  prep_clusters<<<512, 256, 0, stream>>>(clusters, Bws, c2);
  fused_kernel<<<1024, 1024, 0, stream>>>(inputs, Bws, c2, out);
}